// Round 2
// baseline (567.860 us; speedup 1.0000x reference)
//
#include <hip/hip_runtime.h>
#include <hip/hip_bf16.h>

#define SDIM 128
#define NCOL 16384          // SDIM*SDIM
#define ROWS_TOTAL 4096     // 4*1024

using bf16x8 = __attribute__((ext_vector_type(8))) __bf16;
using f32x4  = __attribute__((ext_vector_type(4))) float;

__device__ __forceinline__ ushort f2bf(float f) {
  union { float f; unsigned u; } a; a.f = f;
  unsigned u = a.u;
  unsigned r = (u + 0x7FFFu + ((u >> 16) & 1u)) >> 16;  // RNE
  return (ushort)r;
}

// ---------------- L/R f32 -> bf16 prep ----------------
__global__ __launch_bounds__(256) void k_cvt_lr(const float* __restrict__ L,
                                                const float* __restrict__ R,
                                                ushort* __restrict__ Lb,
                                                ushort* __restrict__ Rb) {
  int i = blockIdx.x * 256 + threadIdx.x;     // float4 index
  const int half = 524288;                    // 2097152 / 4
  const float4* src = (i < half) ? reinterpret_cast<const float4*>(L)
                                 : reinterpret_cast<const float4*>(R);
  ushort* dst = (i < half) ? Lb : Rb;
  int idx = (i < half) ? i : i - half;
  float4 v = src[idx];
  ushort4 o; o.x = f2bf(v.x); o.y = f2bf(v.y); o.z = f2bf(v.z); o.w = f2bf(v.w);
  reinterpret_cast<ushort4*>(dst)[idx] = o;
}

// ---------------- stage 1: T[r][m][j] = sum_k L[m][j][k] * x[r][k*128+m] ----------------
// grid = rowtiles*8 blocks, 256 thr. block: 16 rows x 16 m's.
__global__ __launch_bounds__(256) void k_stage1(const float* __restrict__ x,
                                                const ushort* __restrict__ Lb,
                                                ushort* __restrict__ T,
                                                int rowtiles) {
  unsigned nwg = gridDim.x;
  unsigned wg  = (blockIdx.x & 7u) * (nwg >> 3) + (blockIdx.x >> 3);  // XCD-contiguous
  int rt = wg >> 3;
  int mg = wg & 7;
  int row0 = rt * 16;
  int m0 = mg * 16;

  __shared__ __align__(16) ushort xs[32768];  // [m 16][r 16][k 128] bf16, XOR-swizzled on r

  int tid = threadIdx.x;
  // ---- stage x slice into LDS (transpose m<->(r,k), f32->bf16) ----
  for (int task = tid; task < 512; task += 256) {
    int r = task >> 5, kq = task & 31;
    int k = kq << 2;
    const float4* p4 = reinterpret_cast<const float4*>(
        x + (size_t)(row0 + r) * NCOL + (size_t)k * SDIM + m0);
    ushort vv[4][16];
#pragma unroll
    for (int kk = 0; kk < 4; ++kk) {
#pragma unroll
      for (int q = 0; q < 4; ++q) {
        float4 a = p4[kk * 32 + q];
        vv[kk][q * 4 + 0] = f2bf(a.x); vv[kk][q * 4 + 1] = f2bf(a.y);
        vv[kk][q * 4 + 2] = f2bf(a.z); vv[kk][q * 4 + 3] = f2bf(a.w);
      }
    }
#pragma unroll
    for (int mm = 0; mm < 16; ++mm) {
      int e = ((mm * 16 + r) << 7) + k;
      int idx = e ^ ((r & 7) << 3);
      ushort4 w; w.x = vv[0][mm]; w.y = vv[1][mm]; w.z = vv[2][mm]; w.w = vv[3][mm];
      *reinterpret_cast<ushort4*>(&xs[idx]) = w;
    }
  }
  __syncthreads();

  int wave = tid >> 6, lane = tid & 63;
  int l15 = lane & 15, g = lane >> 4;
  int swz = (l15 & 7) << 3;

  for (int m = 0; m < 16; ++m) {
    // B-frags: B[k][r] from xs, shared across this wave's two j-tiles
    bf16x8 bfrag[4];
#pragma unroll
    for (int ks = 0; ks < 4; ++ks) {
      int e = ((m * 16 + l15) << 7) + ks * 32 + g * 8;
      bfrag[ks] = *reinterpret_cast<const bf16x8*>(&xs[e ^ swz]);
    }
    f32x4 acc0 = {0.f, 0.f, 0.f, 0.f};
    f32x4 acc1 = {0.f, 0.f, 0.f, 0.f};
    const ushort* Lm = Lb + (size_t)(m0 + m) * (SDIM * SDIM);
#pragma unroll
    for (int ks = 0; ks < 4; ++ks) {
      int k = ks * 32 + g * 8;
      bf16x8 a0 = *reinterpret_cast<const bf16x8*>(Lm + (size_t)(wave * 32 + l15) * SDIM + k);
      acc0 = __builtin_amdgcn_mfma_f32_16x16x32_bf16(a0, bfrag[ks], acc0, 0, 0, 0);
      bf16x8 a1 = *reinterpret_cast<const bf16x8*>(Lm + (size_t)(wave * 32 + 16 + l15) * SDIM + k);
      acc1 = __builtin_amdgcn_mfma_f32_16x16x32_bf16(a1, bfrag[ks], acc1, 0, 0, 0);
    }
    // D[j][r]: row j = jtile + g*4 + v, col r = l15.  T[r][m][j], 4 consecutive j -> ushort4
    size_t base = (size_t)(row0 + l15) * NCOL + (size_t)(m0 + m) * SDIM;
    ushort4 o0; o0.x = f2bf(acc0[0]); o0.y = f2bf(acc0[1]);
                o0.z = f2bf(acc0[2]); o0.w = f2bf(acc0[3]);
    *reinterpret_cast<ushort4*>(T + base + wave * 32 + g * 4) = o0;
    ushort4 o1; o1.x = f2bf(acc1[0]); o1.y = f2bf(acc1[1]);
                o1.z = f2bf(acc1[2]); o1.w = f2bf(acc1[3]);
    *reinterpret_cast<ushort4*>(T + base + wave * 32 + 16 + g * 4) = o1;
  }
}

// ---------------- stage 2: out[r][i*128+j] = sum_m R[j][i][m] * T[r][m][j] ----------------
// grid = rowtiles*8 blocks, 256 thr. block: 16 rows x 16 j's.
__global__ __launch_bounds__(256) void k_stage2(const ushort* __restrict__ T,
                                                const ushort* __restrict__ Rb,
                                                float* __restrict__ out,
                                                int rowtiles) {
  unsigned nwg = gridDim.x;
  unsigned wg  = (blockIdx.x & 7u) * (nwg >> 3) + (blockIdx.x >> 3);
  int rt = wg >> 3;
  int jg = wg & 7;
  int row0 = rt * 16;
  int j0 = jg * 16;

  __shared__ __align__(16) ushort ts[32768];  // [jj 16][r 16][m 128] bf16, XOR-swizzled on r

  int tid = threadIdx.x;
  for (int task = tid; task < 512; task += 256) {
    int r = task >> 5, mq = task & 31;
    int m = mq << 2;
    ushort vv[4][16];
#pragma unroll
    for (int mm = 0; mm < 4; ++mm) {
      const ushort4* p = reinterpret_cast<const ushort4*>(
          T + (size_t)(row0 + r) * NCOL + (size_t)(m + mm) * SDIM + j0);
#pragma unroll
      for (int q = 0; q < 4; ++q) {
        ushort4 a = p[q];
        vv[mm][q * 4 + 0] = a.x; vv[mm][q * 4 + 1] = a.y;
        vv[mm][q * 4 + 2] = a.z; vv[mm][q * 4 + 3] = a.w;
      }
    }
#pragma unroll
    for (int jj = 0; jj < 16; ++jj) {
      int e = ((jj * 16 + r) << 7) + m;
      int idx = e ^ ((r & 7) << 3);
      ushort4 w; w.x = vv[0][jj]; w.y = vv[1][jj]; w.z = vv[2][jj]; w.w = vv[3][jj];
      *reinterpret_cast<ushort4*>(&ts[idx]) = w;
    }
  }
  __syncthreads();

  int wave = tid >> 6, lane = tid & 63;
  int l15 = lane & 15, g = lane >> 4;
  int swz = (l15 & 7) << 3;
  int i0a = wave * 32, i0b = wave * 32 + 16;

  for (int jj4 = 0; jj4 < 4; ++jj4) {
    f32x4 acc[4][2];
#pragma unroll
    for (int js = 0; js < 4; ++js) {
      acc[js][0] = {0.f, 0.f, 0.f, 0.f};
      acc[js][1] = {0.f, 0.f, 0.f, 0.f};
    }
#pragma unroll
    for (int js = 0; js < 4; ++js) {
      int jj = jj4 * 4 + js;
      const ushort* Rj = Rb + (size_t)(j0 + jj) * (SDIM * SDIM);
      bf16x8 af[4];
#pragma unroll
      for (int ms = 0; ms < 4; ++ms) {
        int e = ((jj * 16 + l15) << 7) + ms * 32 + g * 8;
        af[ms] = *reinterpret_cast<const bf16x8*>(&ts[e ^ swz]);
      }
#pragma unroll
      for (int ms = 0; ms < 4; ++ms) {
        int k = ms * 32 + g * 8;
        bf16x8 b0 = *reinterpret_cast<const bf16x8*>(Rj + (size_t)(i0a + l15) * SDIM + k);
        acc[js][0] = __builtin_amdgcn_mfma_f32_16x16x32_bf16(af[ms], b0, acc[js][0], 0, 0, 0);
        bf16x8 b1 = *reinterpret_cast<const bf16x8*>(Rj + (size_t)(i0b + l15) * SDIM + k);
        acc[js][1] = __builtin_amdgcn_mfma_f32_16x16x32_bf16(af[ms], b1, acc[js][1], 0, 0, 0);
      }
    }
    // D[r][i]: row r = g*4+v, col i = i0 + l15. batch 4 j's per lane -> float4 store
#pragma unroll
    for (int v = 0; v < 4; ++v) {
      size_t rowbase = (size_t)(row0 + g * 4 + v) * NCOL;
      float4 o0; o0.x = acc[0][0][v]; o0.y = acc[1][0][v];
                 o0.z = acc[2][0][v]; o0.w = acc[3][0][v];
      *reinterpret_cast<float4*>(out + rowbase + (size_t)(i0a + l15) * SDIM + j0 + jj4 * 4) = o0;
      float4 o1; o1.x = acc[0][1][v]; o1.y = acc[1][1][v];
                 o1.z = acc[2][1][v]; o1.w = acc[3][1][v];
      *reinterpret_cast<float4*>(out + rowbase + (size_t)(i0b + l15) * SDIM + j0 + jj4 * 4) = o1;
    }
  }
}

extern "C" void kernel_launch(void* const* d_in, const int* in_sizes, int n_in,
                              void* d_out, int out_size, void* d_ws, size_t ws_size,
                              hipStream_t stream) {
  const float* x = (const float*)d_in[0];
  const float* L = (const float*)d_in[1];
  const float* R = (const float*)d_in[2];
  float* out = (float*)d_out;

  ushort* Lb = (ushort*)d_ws;
  ushort* Rb = Lb + 2097152;
  ushort* T  = Rb + 2097152;
  const size_t lr_bytes = (size_t)2 * 2097152 * 2;
  size_t avail = ws_size > lr_bytes ? ws_size - lr_bytes : 0;
  long long rpc = (long long)(avail / ((size_t)NCOL * 2));  // rows of T that fit
  if (rpc > ROWS_TOTAL) rpc = ROWS_TOTAL;
  rpc &= ~15LL;
  if (rpc < 16) rpc = 16;

  k_cvt_lr<<<4096, 256, 0, stream>>>(L, R, Lb, Rb);

  for (long long row0 = 0; row0 < ROWS_TOTAL; row0 += rpc) {
    long long rows = (ROWS_TOTAL - row0 < rpc) ? (ROWS_TOTAL - row0) : rpc;
    int rowtiles = (int)(rows / 16);
    dim3 grid(rowtiles * 8);
    k_stage1<<<grid, 256, 0, stream>>>(x + row0 * NCOL, Lb, T, rowtiles);
    k_stage2<<<grid, 256, 0, stream>>>(T, Rb, out + row0 * NCOL, rowtiles);
  }
}

// Round 4
// 493.858 us; speedup vs baseline: 1.1498x; 1.1498x over previous
//
#include <hip/hip_runtime.h>
#include <hip/hip_bf16.h>

#define SDIM 128
#define NCOL 16384          // SDIM*SDIM
#define ROWS_TOTAL 4096     // 4*1024

using bf16x8 = __attribute__((ext_vector_type(8))) __bf16;
using su8    = __attribute__((ext_vector_type(8))) ushort;
using f32x4  = __attribute__((ext_vector_type(4))) float;

__device__ __forceinline__ ushort f2bf(float f) {
  union { float f; unsigned u; } a; a.f = f;
  unsigned u = a.u;
  unsigned r = (u + 0x7FFFu + ((u >> 16) & 1u)) >> 16;  // RNE
  return (ushort)r;
}

// ---------------- L/R f32 -> bf16 prep ----------------
__global__ __launch_bounds__(256) void k_cvt_lr(const float* __restrict__ L,
                                                const float* __restrict__ R,
                                                ushort* __restrict__ Lb,
                                                ushort* __restrict__ Rb) {
  int i = blockIdx.x * 256 + threadIdx.x;     // float4 index
  const int half = 524288;                    // 2097152 / 4
  const float4* src = (i < half) ? reinterpret_cast<const float4*>(L)
                                 : reinterpret_cast<const float4*>(R);
  ushort* dst = (i < half) ? Lb : Rb;
  int idx = (i < half) ? i : i - half;
  float4 v = src[idx];
  ushort4 o; o.x = f2bf(v.x); o.y = f2bf(v.y); o.z = f2bf(v.z); o.w = f2bf(v.w);
  reinterpret_cast<ushort4*>(dst)[idx] = o;
}

// ---------------- stage 1: T[r][m][j] = sum_k L[m][j][k] * x[r][k*128+m] ----------------
// grid = rowtiles*16, 256 thr. block: 16 rows x 8 m's. LDS 32 KB.
__global__ __launch_bounds__(256) void k_stage1(const float* __restrict__ x,
                                                const ushort* __restrict__ Lb,
                                                ushort* __restrict__ T,
                                                int rowtiles) {
  unsigned nwg = gridDim.x;
  unsigned wg  = (blockIdx.x & 7u) * (nwg >> 3) + (blockIdx.x >> 3);  // XCD-contiguous
  int rt = wg >> 4;
  int mg = wg & 15;
  int row0 = rt * 16;
  int m0 = mg * 8;

  __shared__ __align__(16) ushort xs[16384];  // [m 8][r 16][k 128], XOR-swizzled on r

  int tid = threadIdx.x;
  // ---- stage x slice into LDS (transpose m<->(r,k), f32->bf16) ----
  for (int t2 = 0; t2 < 2; ++t2) {
    int task = t2 * 256 + tid;                // 512 tasks
    int r = task >> 5, kq = task & 31;
    int k = kq << 2;
    const float4* p4 = reinterpret_cast<const float4*>(
        x + (size_t)(row0 + r) * NCOL + (size_t)k * SDIM + m0);
    ushort vv[4][8];
#pragma unroll
    for (int kk = 0; kk < 4; ++kk) {
      float4 a0 = p4[kk * 32 + 0];
      float4 a1 = p4[kk * 32 + 1];
      vv[kk][0] = f2bf(a0.x); vv[kk][1] = f2bf(a0.y);
      vv[kk][2] = f2bf(a0.z); vv[kk][3] = f2bf(a0.w);
      vv[kk][4] = f2bf(a1.x); vv[kk][5] = f2bf(a1.y);
      vv[kk][6] = f2bf(a1.z); vv[kk][7] = f2bf(a1.w);
    }
#pragma unroll
    for (int mm = 0; mm < 8; ++mm) {
      int e = ((mm * 16 + r) << 7) + k;
      int idx = e ^ ((r & 7) << 3);
      ushort4 w; w.x = vv[0][mm]; w.y = vv[1][mm]; w.z = vv[2][mm]; w.w = vv[3][mm];
      *reinterpret_cast<ushort4*>(&xs[idx]) = w;
    }
  }
  __syncthreads();

  int wave = tid >> 6, lane = tid & 63;
  int l15 = lane & 15, g = lane >> 4;
  int swz = (l15 & 7) << 3;

  for (int m = 0; m < 8; ++m) {
    bf16x8 bfrag[4];
#pragma unroll
    for (int ks = 0; ks < 4; ++ks) {
      int e = ((m * 16 + l15) << 7) + ks * 32 + g * 8;
      bfrag[ks] = *reinterpret_cast<const bf16x8*>(&xs[e ^ swz]);
    }
    f32x4 acc0 = {0.f, 0.f, 0.f, 0.f};
    f32x4 acc1 = {0.f, 0.f, 0.f, 0.f};
    const ushort* Lm = Lb + (size_t)(m0 + m) * NCOL;
#pragma unroll
    for (int ks = 0; ks < 4; ++ks) {
      int k = ks * 32 + g * 8;
      bf16x8 a0 = *reinterpret_cast<const bf16x8*>(Lm + (size_t)(wave * 32 + l15) * SDIM + k);
      acc0 = __builtin_amdgcn_mfma_f32_16x16x32_bf16(a0, bfrag[ks], acc0, 0, 0, 0);
      bf16x8 a1 = *reinterpret_cast<const bf16x8*>(Lm + (size_t)(wave * 32 + 16 + l15) * SDIM + k);
      acc1 = __builtin_amdgcn_mfma_f32_16x16x32_bf16(a1, bfrag[ks], acc1, 0, 0, 0);
    }
    // D[j][r]: row j = wave*32 + {0,16} + g*4+v, col r = l15
    size_t base = (size_t)(row0 + l15) * NCOL + (size_t)(m0 + m) * SDIM;
    ushort4 o0; o0.x = f2bf(acc0[0]); o0.y = f2bf(acc0[1]);
                o0.z = f2bf(acc0[2]); o0.w = f2bf(acc0[3]);
    *reinterpret_cast<ushort4*>(T + base + wave * 32 + g * 4) = o0;
    ushort4 o1; o1.x = f2bf(acc1[0]); o1.y = f2bf(acc1[1]);
                o1.z = f2bf(acc1[2]); o1.w = f2bf(acc1[3]);
    *reinterpret_cast<ushort4*>(T + base + wave * 32 + 16 + g * 4) = o1;
  }
}

// ---------------- stage 2: out[r][i*128+j] = sum_m R[j][i][m] * T[r][m][j] ----------------
// grid = rowtiles*16, 256 thr. block: 16 rows x 16 j's x 64 i's. LDS 32 KB, 2 m-phases.
__global__ __launch_bounds__(256) void k_stage2(const ushort* __restrict__ T,
                                                const ushort* __restrict__ Rb,
                                                float* __restrict__ out,
                                                int rowtiles) {
  unsigned nwg = gridDim.x;
  unsigned wg  = (blockIdx.x & 7u) * (nwg >> 3) + (blockIdx.x >> 3);
  int rt = wg >> 4;
  int rem = wg & 15;
  int jg = rem >> 1;
  int ih = rem & 1;              // i-half: ih-partners + adjacent jg share L2 lines
  int row0 = rt * 16;
  int j0 = jg * 16;

  __shared__ __align__(16) ushort ts[16384];  // [jj 16][r 16][ml 64], XOR-swizzled on r

  int tid = threadIdx.x;
  int wave = tid >> 6, lane = tid & 63;
  int l15 = lane & 15, g = lane >> 4;
  int swz = (l15 & 7) << 3;
  int ibase = ih * 64 + wave * 16;

  f32x4 acc[16];
#pragma unroll
  for (int jj = 0; jj < 16; ++jj) acc[jj] = {0.f, 0.f, 0.f, 0.f};

  for (int ph = 0; ph < 2; ++ph) {
    int mh0 = ph * 64;
    if (ph) __syncthreads();    // protect ts reuse
    // ---- stage T[r][mh0+ml][j0:j0+16] -> ts[jj][r][ml] ----
#pragma unroll
    for (int t2 = 0; t2 < 2; ++t2) {
      int task = t2 * 256 + tid;              // 512 tasks: 16 r x 32 m-pairs
      int r = task >> 5, mq = task & 31;
      const ushort* src = T + (size_t)(row0 + r) * NCOL + (size_t)(mh0 + mq * 2) * SDIM + j0;
      su8 v0 = *reinterpret_cast<const su8*>(src);          // m row even, jj 0..7
      su8 v1 = *reinterpret_cast<const su8*>(src + 8);      // m row even, jj 8..15
      su8 v2 = *reinterpret_cast<const su8*>(src + SDIM);   // m row odd
      su8 v3 = *reinterpret_cast<const su8*>(src + SDIM + 8);
      int ml = mq * 2;
#pragma unroll
      for (int jj = 0; jj < 8; ++jj) {
        int e0 = (((jj * 16 + r) << 6) + ml) ^ ((r & 7) << 3);
        ushort2 w0; w0.x = v0[jj]; w0.y = v2[jj];
        *reinterpret_cast<ushort2*>(&ts[e0]) = w0;
        int e1 = ((((jj + 8) * 16 + r) << 6) + ml) ^ ((r & 7) << 3);
        ushort2 w1; w1.x = v1[jj]; w1.y = v3[jj];
        *reinterpret_cast<ushort2*>(&ts[e1]) = w1;
      }
    }
    __syncthreads();
    // ---- compute: acc[jj] += U[r][m-half] x R[j][i][m-half] ----
#pragma unroll
    for (int jj = 0; jj < 16; ++jj) {
      const ushort* Rj = Rb + (size_t)(j0 + jj) * NCOL + (size_t)(ibase + l15) * SDIM + mh0;
#pragma unroll
      for (int ks = 0; ks < 2; ++ks) {
        int e = ((jj * 16 + l15) << 6) + ks * 32 + g * 8;
        bf16x8 af = *reinterpret_cast<const bf16x8*>(&ts[e ^ swz]);
        bf16x8 bf = *reinterpret_cast<const bf16x8*>(Rj + ks * 32 + g * 8);
        acc[jj] = __builtin_amdgcn_mfma_f32_16x16x32_bf16(af, bf, acc[jj], 0, 0, 0);
      }
    }
  }

  // ---- epilogue: each lane owns full 64B out lines, written back-to-back ----
  // D[row=r][col=i]: r = g*4+v, i = ibase+l15; lane's 16 jj = 64 B contiguous.
#pragma unroll
  for (int v = 0; v < 4; ++v) {
    float* dst = out + (size_t)(row0 + g * 4 + v) * NCOL + (size_t)(ibase + l15) * SDIM + j0;
#pragma unroll
    for (int q = 0; q < 4; ++q) {
      float4 o; o.x = acc[q * 4 + 0][v]; o.y = acc[q * 4 + 1][v];
                o.z = acc[q * 4 + 2][v]; o.w = acc[q * 4 + 3][v];
      *reinterpret_cast<float4*>(dst + q * 4) = o;
    }
  }
}

extern "C" void kernel_launch(void* const* d_in, const int* in_sizes, int n_in,
                              void* d_out, int out_size, void* d_ws, size_t ws_size,
                              hipStream_t stream) {
  const float* x = (const float*)d_in[0];
  const float* L = (const float*)d_in[1];
  const float* R = (const float*)d_in[2];
  float* out = (float*)d_out;

  ushort* Lb = (ushort*)d_ws;
  ushort* Rb = Lb + 2097152;
  ushort* T  = Rb + 2097152;
  const size_t lr_bytes = (size_t)2 * 2097152 * 2;
  size_t avail = ws_size > lr_bytes ? ws_size - lr_bytes : 0;
  long long rpc = (long long)(avail / ((size_t)NCOL * 2));  // rows of T that fit
  if (rpc > ROWS_TOTAL) rpc = ROWS_TOTAL;
  rpc &= ~15LL;
  if (rpc < 16) rpc = 16;

  k_cvt_lr<<<4096, 256, 0, stream>>>(L, R, Lb, Rb);

  for (long long row0 = 0; row0 < ROWS_TOTAL; row0 += rpc) {
    long long rows = (ROWS_TOTAL - row0 < rpc) ? (ROWS_TOTAL - row0) : rpc;
    int rowtiles = (int)(rows / 16);
    dim3 grid(rowtiles * 16);
    k_stage1<<<grid, 256, 0, stream>>>(x + row0 * NCOL, Lb, T, rowtiles);
    k_stage2<<<grid, 256, 0, stream>>>(T, Rb, out + row0 * NCOL, rowtiles);
  }
}

// Round 5
// 472.627 us; speedup vs baseline: 1.2015x; 1.0449x over previous
//
#include <hip/hip_runtime.h>
#include <hip/hip_bf16.h>

#define SDIM 128
#define NCOL 16384          // SDIM*SDIM
#define ROWS_TOTAL 4096     // 4*1024

using bf16x8 = __attribute__((ext_vector_type(8))) __bf16;
using su8    = __attribute__((ext_vector_type(8))) ushort;
using f32x4  = __attribute__((ext_vector_type(4))) float;

__device__ __forceinline__ ushort f2bf(float f) {
  union { float f; unsigned u; } a; a.f = f;
  unsigned u = a.u;
  unsigned r = (u + 0x7FFFu + ((u >> 16) & 1u)) >> 16;  // RNE
  return (ushort)r;
}

// ---------------- L/R f32 -> bf16 prep ----------------
__global__ __launch_bounds__(256) void k_cvt_lr(const float* __restrict__ L,
                                                const float* __restrict__ R,
                                                ushort* __restrict__ Lb,
                                                ushort* __restrict__ Rb) {
  int i = blockIdx.x * 256 + threadIdx.x;     // float4 index
  const int half = 524288;                    // 2097152 / 4
  const float4* src = (i < half) ? reinterpret_cast<const float4*>(L)
                                 : reinterpret_cast<const float4*>(R);
  ushort* dst = (i < half) ? Lb : Rb;
  int idx = (i < half) ? i : i - half;
  float4 v = src[idx];
  ushort4 o; o.x = f2bf(v.x); o.y = f2bf(v.y); o.z = f2bf(v.z); o.w = f2bf(v.w);
  reinterpret_cast<ushort4*>(dst)[idx] = o;
}

// ---------------- stage 1: T[r][m][j] = sum_k L[m][j][k] * x[r][k*128+m] ----------------
// grid = rowtiles*16, 256 thr. block: 16 rows x 8 m's. LDS 32 KB.
// Software-pipelined: L-frags for m+1 prefetched during m's MFMAs.
__global__ __launch_bounds__(256) void k_stage1(const float* __restrict__ x,
                                                const ushort* __restrict__ Lb,
                                                ushort* __restrict__ T,
                                                int rowtiles) {
  unsigned nwg = gridDim.x;
  unsigned wg  = (blockIdx.x & 7u) * (nwg >> 3) + (blockIdx.x >> 3);  // XCD-contiguous
  int rt = wg >> 4;
  int mg = wg & 15;
  int row0 = rt * 16;
  int m0 = mg * 8;

  __shared__ __align__(16) ushort xs[16384];  // [m 8][r 16][k 128], XOR-swizzled on r

  int tid = threadIdx.x;
  // ---- stage x slice into LDS (transpose m<->(r,k), f32->bf16) ----
  for (int t2 = 0; t2 < 2; ++t2) {
    int task = t2 * 256 + tid;                // 512 tasks
    int r = task >> 5, kq = task & 31;
    int k = kq << 2;
    const float4* p4 = reinterpret_cast<const float4*>(
        x + (size_t)(row0 + r) * NCOL + (size_t)k * SDIM + m0);
    ushort vv[4][8];
#pragma unroll
    for (int kk = 0; kk < 4; ++kk) {
      float4 a0 = p4[kk * 32 + 0];
      float4 a1 = p4[kk * 32 + 1];
      vv[kk][0] = f2bf(a0.x); vv[kk][1] = f2bf(a0.y);
      vv[kk][2] = f2bf(a0.z); vv[kk][3] = f2bf(a0.w);
      vv[kk][4] = f2bf(a1.x); vv[kk][5] = f2bf(a1.y);
      vv[kk][6] = f2bf(a1.z); vv[kk][7] = f2bf(a1.w);
    }
#pragma unroll
    for (int mm = 0; mm < 8; ++mm) {
      int e = ((mm * 16 + r) << 7) + k;
      int idx = e ^ ((r & 7) << 3);
      ushort4 w; w.x = vv[0][mm]; w.y = vv[1][mm]; w.z = vv[2][mm]; w.w = vv[3][mm];
      *reinterpret_cast<ushort4*>(&xs[idx]) = w;
    }
  }
  __syncthreads();

  int wave = tid >> 6, lane = tid & 63;
  int l15 = lane & 15, g = lane >> 4;
  int swz = (l15 & 7) << 3;

  // Per-lane L base: row (wave*32 [+16] + l15), col k = ks*32 + g*8
  const ushort* Lbase = Lb + (size_t)m0 * NCOL + (size_t)(wave * 32 + l15) * SDIM + g * 8;

  bf16x8 laA[8], laB[8];      // ping-pong L-frag rings (static idx via full unroll)
#pragma unroll
  for (int ks = 0; ks < 4; ++ks) {
    laA[ks]     = *reinterpret_cast<const bf16x8*>(Lbase + ks * 32);
    laA[ks + 4] = *reinterpret_cast<const bf16x8*>(Lbase + 16 * SDIM + ks * 32);
  }

#pragma unroll
  for (int m = 0; m < 8; ++m) {
    const bool odd = (m & 1) != 0;
    // ---- prefetch L-frags for m+1 into the other ring buffer ----
    if (m < 7) {
      const ushort* Ln = Lbase + (size_t)(m + 1) * NCOL;
#pragma unroll
      for (int ks = 0; ks < 4; ++ks) {
        bf16x8 lo = *reinterpret_cast<const bf16x8*>(Ln + ks * 32);
        bf16x8 hi = *reinterpret_cast<const bf16x8*>(Ln + 16 * SDIM + ks * 32);
        if (odd) { laA[ks] = lo; laA[ks + 4] = hi; }
        else     { laB[ks] = lo; laB[ks + 4] = hi; }
      }
    }
    // ---- B-frags from LDS ----
    bf16x8 bfrag[4];
#pragma unroll
    for (int ks = 0; ks < 4; ++ks) {
      int e = ((m * 16 + l15) << 7) + ks * 32 + g * 8;
      bfrag[ks] = *reinterpret_cast<const bf16x8*>(&xs[e ^ swz]);
    }
    // ---- MFMA ----
    f32x4 acc0 = {0.f, 0.f, 0.f, 0.f};
    f32x4 acc1 = {0.f, 0.f, 0.f, 0.f};
#pragma unroll
    for (int ks = 0; ks < 4; ++ks) {
      bf16x8 a0 = odd ? laB[ks] : laA[ks];
      bf16x8 a1 = odd ? laB[ks + 4] : laA[ks + 4];
      acc0 = __builtin_amdgcn_mfma_f32_16x16x32_bf16(a0, bfrag[ks], acc0, 0, 0, 0);
      acc1 = __builtin_amdgcn_mfma_f32_16x16x32_bf16(a1, bfrag[ks], acc1, 0, 0, 0);
    }
    // D[j][r]: row j = wave*32 + {0,16} + g*4+v, col r = l15
    size_t base = (size_t)(row0 + l15) * NCOL + (size_t)(m0 + m) * SDIM;
    ushort4 o0; o0.x = f2bf(acc0[0]); o0.y = f2bf(acc0[1]);
                o0.z = f2bf(acc0[2]); o0.w = f2bf(acc0[3]);
    *reinterpret_cast<ushort4*>(T + base + wave * 32 + g * 4) = o0;
    ushort4 o1; o1.x = f2bf(acc1[0]); o1.y = f2bf(acc1[1]);
                o1.z = f2bf(acc1[2]); o1.w = f2bf(acc1[3]);
    *reinterpret_cast<ushort4*>(T + base + wave * 32 + 16 + g * 4) = o1;
  }
}

// ---------------- stage 2: out[r][i*128+j] = sum_m R[j][i][m] * T[r][m][j] ----------------
// grid = rowtiles*16, 256 thr. block: 16 rows x 16 j's x 64 i's. LDS 32 KB, 2 m-phases.
// Compute loop: 2-deep R-frag prefetch ring, 1:1 load/MFMA interleave.
__global__ __launch_bounds__(256) void k_stage2(const ushort* __restrict__ T,
                                                const ushort* __restrict__ Rb,
                                                float* __restrict__ out,
                                                int rowtiles) {
  unsigned nwg = gridDim.x;
  unsigned wg  = (blockIdx.x & 7u) * (nwg >> 3) + (blockIdx.x >> 3);
  int rt = wg >> 4;
  int rem = wg & 15;
  int jg = rem >> 1;
  int ih = rem & 1;              // i-half
  int row0 = rt * 16;
  int j0 = jg * 16;

  __shared__ __align__(16) ushort ts[16384];  // [jj 16][r 16][ml 64], XOR-swizzled on r

  int tid = threadIdx.x;
  int wave = tid >> 6, lane = tid & 63;
  int l15 = lane & 15, g = lane >> 4;
  int swz = (l15 & 7) << 3;
  int ibase = ih * 64 + wave * 16;

  f32x4 acc[16];
#pragma unroll
  for (int jj = 0; jj < 16; ++jj) acc[jj] = {0.f, 0.f, 0.f, 0.f};

  for (int ph = 0; ph < 2; ++ph) {
    int mh0 = ph * 64;
    if (ph) __syncthreads();    // protect ts reuse
    // ---- stage T[r][mh0+ml][j0:j0+16] -> ts[jj][r][ml] ----
#pragma unroll
    for (int t2 = 0; t2 < 2; ++t2) {
      int task = t2 * 256 + tid;              // 512 tasks: 16 r x 32 m-pairs
      int r = task >> 5, mq = task & 31;
      const ushort* src = T + (size_t)(row0 + r) * NCOL + (size_t)(mh0 + mq * 2) * SDIM + j0;
      su8 v0 = *reinterpret_cast<const su8*>(src);          // m row even, jj 0..7
      su8 v1 = *reinterpret_cast<const su8*>(src + 8);      // m row even, jj 8..15
      su8 v2 = *reinterpret_cast<const su8*>(src + SDIM);   // m row odd
      su8 v3 = *reinterpret_cast<const su8*>(src + SDIM + 8);
      int ml = mq * 2;
#pragma unroll
      for (int jj = 0; jj < 8; ++jj) {
        int e0 = (((jj * 16 + r) << 6) + ml) ^ ((r & 7) << 3);
        ushort2 w0; w0.x = v0[jj]; w0.y = v2[jj];
        *reinterpret_cast<ushort2*>(&ts[e0]) = w0;
        int e1 = ((((jj + 8) * 16 + r) << 6) + ml) ^ ((r & 7) << 3);
        ushort2 w1; w1.x = v1[jj]; w1.y = v3[jj];
        *reinterpret_cast<ushort2*>(&ts[e1]) = w1;
      }
    }
    __syncthreads();
    // ---- compute: 2-deep prefetch of R, interleaved with ds_read + MFMA ----
    const ushort* Rp = Rb + (size_t)j0 * NCOL + (size_t)(ibase + l15) * SDIM + mh0 + g * 8;
    bf16x8 rf0a = *reinterpret_cast<const bf16x8*>(Rp);
    bf16x8 rf0b = *reinterpret_cast<const bf16x8*>(Rp + 32);
    bf16x8 rf1a = *reinterpret_cast<const bf16x8*>(Rp + NCOL);
    bf16x8 rf1b = *reinterpret_cast<const bf16x8*>(Rp + NCOL + 32);
#pragma unroll
    for (int jj = 0; jj < 16; ++jj) {
      bf16x8 b0 = (jj & 1) ? rf1a : rf0a;
      bf16x8 b1 = (jj & 1) ? rf1b : rf0b;
      if (jj < 14) {
        const ushort* Rn = Rp + (size_t)(jj + 2) * NCOL;
        bf16x8 na = *reinterpret_cast<const bf16x8*>(Rn);
        bf16x8 nb = *reinterpret_cast<const bf16x8*>(Rn + 32);
        if (jj & 1) { rf1a = na; rf1b = nb; }
        else        { rf0a = na; rf0b = nb; }
      }
      int eb = ((jj * 16 + l15) << 6) + g * 8;
      bf16x8 af0 = *reinterpret_cast<const bf16x8*>(&ts[eb ^ swz]);
      bf16x8 af1 = *reinterpret_cast<const bf16x8*>(&ts[(eb + 32) ^ swz]);
      acc[jj] = __builtin_amdgcn_mfma_f32_16x16x32_bf16(af0, b0, acc[jj], 0, 0, 0);
      acc[jj] = __builtin_amdgcn_mfma_f32_16x16x32_bf16(af1, b1, acc[jj], 0, 0, 0);
    }
  }

  // ---- epilogue: each lane owns full 64B out lines, written back-to-back ----
  // D[row=r][col=i]: r = g*4+v, i = ibase+l15; lane's 16 jj = 64 B contiguous.
#pragma unroll
  for (int v = 0; v < 4; ++v) {
    float* dst = out + (size_t)(row0 + g * 4 + v) * NCOL + (size_t)(ibase + l15) * SDIM + j0;
#pragma unroll
    for (int q = 0; q < 4; ++q) {
      float4 o; o.x = acc[q * 4 + 0][v]; o.y = acc[q * 4 + 1][v];
                o.z = acc[q * 4 + 2][v]; o.w = acc[q * 4 + 3][v];
      *reinterpret_cast<float4*>(dst + q * 4) = o;
    }
  }
}

extern "C" void kernel_launch(void* const* d_in, const int* in_sizes, int n_in,
                              void* d_out, int out_size, void* d_ws, size_t ws_size,
                              hipStream_t stream) {
  const float* x = (const float*)d_in[0];
  const float* L = (const float*)d_in[1];
  const float* R = (const float*)d_in[2];
  float* out = (float*)d_out;

  ushort* Lb = (ushort*)d_ws;
  ushort* Rb = Lb + 2097152;
  ushort* T  = Rb + 2097152;
  const size_t lr_bytes = (size_t)2 * 2097152 * 2;
  size_t avail = ws_size > lr_bytes ? ws_size - lr_bytes : 0;
  long long rpc = (long long)(avail / ((size_t)NCOL * 2));  // rows of T that fit
  if (rpc > ROWS_TOTAL) rpc = ROWS_TOTAL;
  rpc &= ~15LL;
  if (rpc < 16) rpc = 16;

  k_cvt_lr<<<4096, 256, 0, stream>>>(L, R, Lb, Rb);

  for (long long row0 = 0; row0 < ROWS_TOTAL; row0 += rpc) {
    long long rows = (ROWS_TOTAL - row0 < rpc) ? (ROWS_TOTAL - row0) : rpc;
    int rowtiles = (int)(rows / 16);
    dim3 grid(rowtiles * 16);
    k_stage1<<<grid, 256, 0, stream>>>(x + row0 * NCOL, Lb, T, rowtiles);
    k_stage2<<<grid, 256, 0, stream>>>(T, Rb, out + row0 * NCOL, rowtiles);
  }
}